// Round 8
// baseline (219.957 us; speedup 1.0000x reference)
//
#include <hip/hip_runtime.h>
#include <stdint.h>

// Problem constants: B=1, N=4096, C=256, H=8, D=64, H*D=512
#define NN 4096
#define CC 256
#define HD 512
#define DD 64
#define KSPLIT 3               // attn: 64 k-tiles -> 21/21/22, grid 1536 = 6 blocks/CU
#define KSPLIT_O 4             // outproj: HD=512 -> 4 x 128

typedef __attribute__((ext_vector_type(8))) short short8;
typedef __attribute__((ext_vector_type(4))) float floatx4;

__device__ __forceinline__ unsigned short f2bf(float x) {
    union { float f; unsigned int u; } v; v.f = x;
    unsigned int u = v.u + 0x7fffu + ((v.u >> 16) & 1u);
    return (unsigned short)(u >> 16);
}
__device__ __forceinline__ float bf2f(unsigned short s) {
    union { unsigned int u; float f; } v; v.u = ((unsigned int)s) << 16;
    return v.f;
}

// Pack two f32 -> bf16x2 (lo = first arg), RNE. HW instr on gfx950.
#if defined(__has_builtin) && __has_builtin(__builtin_amdgcn_cvt_pk_bf16_f32)
typedef __attribute__((ext_vector_type(2))) __bf16 bf16x2_t;
__device__ __forceinline__ unsigned int pack2bf(float a, float b) {
    union { bf16x2_t v; unsigned int u; } x;
    x.v = __builtin_amdgcn_cvt_pk_bf16_f32(a, b);
    return x.u;
}
#else
__device__ __forceinline__ unsigned int pack2bf(float a, float b) {
    return ((unsigned int)f2bf(b) << 16) | (unsigned int)f2bf(a);
}
#endif

// Async global->LDS, 16 B per lane; LDS dest = wave-uniform base + lane*16.
#define GLOAD_LDS(gp, lp) __builtin_amdgcn_global_load_lds(                    \
    (__attribute__((address_space(1))) void*)(gp),                             \
    (__attribute__((address_space(3))) void*)(lp), 16, 0, 0)

// ---------------------------------------------------------------------------
// Kernel 0: fp32 -> bf16 prep. z selects region. wq pre-scaled by 0.125.
// ---------------------------------------------------------------------------
__global__ __launch_bounds__(256) void prep_kernel(
    const float* __restrict__ qx, const float* __restrict__ kx,
    const float* __restrict__ vx,
    const float* __restrict__ wq, const float* __restrict__ wk,
    const float* __restrict__ wv, const float* __restrict__ wg,
    const float* __restrict__ wo,
    unsigned short* __restrict__ qxb, unsigned short* __restrict__ kxb,
    unsigned short* __restrict__ vxb, unsigned short* __restrict__ Wb,
    unsigned short* __restrict__ wob)
{
    const int z = blockIdx.y;
    const float* src; unsigned short* dst; int n; float s = 1.0f;
    switch (z) {
        case 0: src = qx; dst = qxb; n = NN * CC; break;
        case 1: src = kx; dst = kxb; n = NN * CC; break;
        case 2: src = vx; dst = vxb; n = NN * CC; break;
        case 3: src = wq; dst = Wb;               n = HD * CC; s = 0.125f; break;
        case 4: src = wk; dst = Wb + 1 * HD * CC; n = HD * CC; break;
        case 5: src = wv; dst = Wb + 2 * HD * CC; n = HD * CC; break;
        case 6: src = wg; dst = Wb + 3 * HD * CC; n = HD * CC; break;
        default: src = wo; dst = wob;             n = CC * HD; break;
    }
    int i = (blockIdx.x * 256 + threadIdx.x) * 4;
    if (i < n) {
        float4 v = *(const float4*)&src[i];
        ushort4 p;
        p.x = f2bf(v.x * s); p.y = f2bf(v.y * s);
        p.z = f2bf(v.z * s); p.w = f2bf(v.w * s);
        *(ushort4*)&dst[i] = p;
    }
}

// ---------------------------------------------------------------------------
// Kernel 1: fused projection GEMM. X[4096][256]bf16 @ Wb[2048][256]^T.
// Tile 64x128 -> grid (64,16) = 1024 blocks = 4 blocks/CU (one full round).
// Wave w owns M-rows [w*16,w*16+16) x all 128 N-cols: 16 MFMA per k-iter.
// global_load_lds staging, unpadded rows + XOR chunk swizzle (slot j of row
// r holds source chunk j^(r&7)).
// ---------------------------------------------------------------------------
__global__ __launch_bounds__(256, 4) void proj_kernel(
    const unsigned short* __restrict__ qxb, const unsigned short* __restrict__ kxb,
    const unsigned short* __restrict__ vxb, const unsigned short* __restrict__ Wb,
    const float* __restrict__ bg,
    unsigned short* __restrict__ Qb, unsigned short* __restrict__ Kb,
    unsigned short* __restrict__ VbT, unsigned short* __restrict__ Gb)
{
    const int m0 = blockIdx.x * 64;
    const int nb = blockIdx.y;
    const int n0 = nb * 128;
    const int mode = nb >> 2;
    const unsigned short* X = (mode == 1) ? kxb : (mode == 2) ? vxb : qxb;

    const int tid = threadIdx.x;
    const int wid = tid >> 6;
    const int lane = tid & 63;
    const int quad = lane >> 4;
    const int ln = lane & 15;
    const int lnx = ln & 7;

    // Xs 64x64 (8 KB) + Ws 128x64 (16 KB) = 24 KB; transpose scratch (128x72
    // shorts = 18 KB) reuses the buffer after the final compute barrier.
    __shared__ __align__(16) unsigned short smem[64 * 64 + 128 * 64];
    unsigned short* Xs = smem;
    unsigned short* Ws = smem + 64 * 64;

    floatx4 acc[8] = {};

    for (int k0 = 0; k0 < CC; k0 += 64) {
        // X: wave w stages rows [w*16, w*16+16) -> 2 GLOADs
        #pragma unroll
        for (int t = 0; t < 2; t++) {
            int row = wid * 16 + t * 8 + (lane >> 3);
            int c = (lane & 7) ^ (lane >> 3);
            GLOAD_LDS(&X[(size_t)(m0 + row) * CC + k0 + c * 8],
                      &Xs[(wid * 16 + t * 8) * 64]);
        }
        // W: wave w stages rows [w*32, w*32+32) -> 4 GLOADs
        #pragma unroll
        for (int t = 0; t < 4; t++) {
            int row = wid * 32 + t * 8 + (lane >> 3);
            int c = (lane & 7) ^ (lane >> 3);
            GLOAD_LDS(&Wb[(size_t)(n0 + row) * CC + k0 + c * 8],
                      &Ws[(wid * 32 + t * 8) * 64]);
        }
        __syncthreads();

        #pragma unroll
        for (int ks = 0; ks < 64; ks += 32) {
            const int cb = ks >> 3;    // 0 or 4
            short8 a = *(const short8*)&Xs[(wid * 16 + ln) * 64 +
                                           (((quad ^ cb) ^ lnx) * 8)];
            #pragma unroll
            for (int j = 0; j < 8; j++) {
                short8 b = *(const short8*)&Ws[(j * 16 + ln) * 64 +
                                               (((quad ^ cb) ^ lnx) * 8)];
                acc[j] = __builtin_amdgcn_mfma_f32_16x16x32_bf16(a, b, acc[j], 0, 0, 0);
            }
        }
        __syncthreads();
    }

    const int subn = nb & 3;
    if (mode != 2) {
        unsigned short* Out = (mode == 0) ? Qb : (mode == 1) ? Kb : Gb;
        #pragma unroll
        for (int j = 0; j < 8; j++) {
            int col = subn * 128 + j * 16 + ln;
            float bgv = (mode == 3) ? bg[col] : 0.0f;
            #pragma unroll
            for (int r = 0; r < 4; r++) {
                int row = m0 + wid * 16 + quad * 4 + r;
                float v = acc[j][r];
                if (mode == 3) v = 1.0f / (1.0f + __expf(-(v + bgv)));
                Out[(size_t)row * HD + col] = f2bf(v);
            }
        }
    } else {
        // V: transpose through smem scratch [128 cols][64 rows], stride 72
        #pragma unroll
        for (int j = 0; j < 8; j++) {
            int cl = j * 16 + ln;
            #pragma unroll
            for (int r = 0; r < 4; r++) {
                int rl = wid * 16 + quad * 4 + r;
                smem[cl * 72 + rl] = f2bf(acc[j][r]);
            }
        }
        __syncthreads();
        #pragma unroll
        for (int it = 0; it < 4; it++) {
            int idx = it * 256 + tid;       // 1024 chunks: 128 cols x 8 chunks
            int c = idx >> 3, ch = idx & 7;
            short8 vv = *(const short8*)&smem[c * 72 + ch * 8];
            *(short8*)&VbT[(size_t)(subn * 128 + c) * NN + m0 + ch * 8] = vv;
        }
    }
}

// ---------------------------------------------------------------------------
// Kernel 2: flash attention, split-K=3 (tiles 21/21/22), Tk=64, Q in regs.
// global_load_lds staging for K/V (unpadded + XOR swizzle); bias enters via
// MFMA C-operand init; Ps written via v_cvt_pk_bf16_f32.
// LDS 25.6 KB -> 6 blocks/CU; grid 1536 = exactly 6/CU (no tail).
// ---------------------------------------------------------------------------
__global__ __launch_bounds__(256, 6) void attn_kernel(
    const unsigned short* __restrict__ Qb, const unsigned short* __restrict__ Kb,
    const unsigned short* __restrict__ VbT,
    const float* __restrict__ bias,
    unsigned short* __restrict__ Opart, float* __restrict__ Lpart)
{
    const int h = blockIdx.y;
    const int q0 = blockIdx.x * 64;
    const int sp = blockIdx.z;
    const int tbeg = (sp * 64) / KSPLIT;
    const int tend = ((sp + 1) * 64) / KSPLIT;
    const int tid = threadIdx.x;
    const int wid = tid >> 6;
    const int lane = tid & 63;
    const int quad = lane >> 4;
    const int ln = lane & 15;
    const int lnx = ln & 7;

    __shared__ __align__(16) unsigned short Ks[64 * 64];   // 8 KB, swizzled
    __shared__ __align__(16) unsigned short Vs[64 * 64];   // 8 KB, swizzled [d][key]
    __shared__ __align__(16) unsigned short Ps[64 * 72];   // 9 KB, padded

    const int qrow = q0 + wid * 16 + ln;
    short8 qa0 = *(const short8*)&Qb[(size_t)qrow * HD + h * DD + quad * 8];
    short8 qa1 = *(const short8*)&Qb[(size_t)qrow * HD + h * DD + 32 + quad * 8];

    floatx4 O[4] = {};
    float lsum[4] = {0.0f, 0.0f, 0.0f, 0.0f};

    for (int kt = tbeg; kt < tend; kt++) {
        const int k0 = kt * 64;
        #pragma unroll
        for (int t = 0; t < 2; t++) {
            int row = wid * 16 + t * 8 + (lane >> 3);
            int c = (lane & 7) ^ (lane >> 3);
            GLOAD_LDS(&Kb[(size_t)(k0 + row) * HD + h * DD + c * 8],
                      &Ks[(wid * 16 + t * 8) * 64]);
            GLOAD_LDS(&VbT[(size_t)(h * DD + row) * NN + k0 + c * 8],
                      &Vs[(wid * 16 + t * 8) * 64]);
        }

        float bv[4][4];
        #pragma unroll
        for (int r = 0; r < 4; r++) {
            const float* brow = &bias[(size_t)(q0 + wid * 16 + quad * 4 + r) * NN + k0];
            #pragma unroll
            for (int n = 0; n < 4; n++) bv[r][n] = brow[n * 16 + ln];
        }
        __syncthreads();

        floatx4 S[4];
        #pragma unroll
        for (int n = 0; n < 4; n++)
            S[n] = (floatx4){bv[0][n], bv[1][n], bv[2][n], bv[3][n]};
        #pragma unroll
        for (int n = 0; n < 4; n++) {
            short8 b0 = *(const short8*)&Ks[(n * 16 + ln) * 64 + ((quad ^ lnx) * 8)];
            S[n] = __builtin_amdgcn_mfma_f32_16x16x32_bf16(qa0, b0, S[n], 0, 0, 0);
            short8 b1 = *(const short8*)&Ks[(n * 16 + ln) * 64 + (((quad ^ 4) ^ lnx) * 8)];
            S[n] = __builtin_amdgcn_mfma_f32_16x16x32_bf16(qa1, b1, S[n], 0, 0, 0);
        }

        #pragma unroll
        for (int r = 0; r < 4; r++) {
            int prow = (wid * 16 + quad * 4 + r) * 72;
            #pragma unroll
            for (int n = 0; n < 4; n += 2) {
                float p0 = __expf(S[n][r]);
                float p1 = __expf(S[n + 1][r]);
                lsum[r] += p0 + p1;
                unsigned int pk = pack2bf(p0, p1);
                Ps[prow + n * 16 + ln] = (unsigned short)(pk & 0xffffu);
                Ps[prow + (n + 1) * 16 + ln] = (unsigned short)(pk >> 16);
            }
        }
        // No barrier: Ps rows are wave-private.

        #pragma unroll
        for (int ks = 0; ks < 64; ks += 32) {
            const int cb = ks >> 3;
            short8 a = *(const short8*)&Ps[(wid * 16 + ln) * 72 + ks + quad * 8];
            #pragma unroll
            for (int nd = 0; nd < 4; nd++) {
                short8 b = *(const short8*)&Vs[(nd * 16 + ln) * 64 +
                                               (((quad ^ cb) ^ lnx) * 8)];
                O[nd] = __builtin_amdgcn_mfma_f32_16x16x32_bf16(a, b, O[nd], 0, 0, 0);
            }
        }
        __syncthreads();
    }

    #pragma unroll
    for (int r = 0; r < 4; r++) {
        #pragma unroll
        for (int off = 1; off < 16; off <<= 1)
            lsum[r] += __shfl_xor(lsum[r], off);
        int grow = q0 + wid * 16 + quad * 4 + r;
        size_t base = ((size_t)(sp * 8 + h) * NN + grow) * 64;
        #pragma unroll
        for (int nd = 0; nd < 4; nd++)
            Opart[base + nd * 16 + ln] = f2bf(O[nd][r]);
        if (ln == 0)
            Lpart[(size_t)(sp * 8 + h) * NN + grow] = lsum[r];
    }
}

// ---------------------------------------------------------------------------
// Kernel 2b: combine split-K partials, normalize, gate -> OG bf16 [4096][512]
// ---------------------------------------------------------------------------
__global__ __launch_bounds__(256) void combine_kernel(
    const unsigned short* __restrict__ Opart, const float* __restrict__ Lpart,
    const unsigned short* __restrict__ Gb, unsigned short* __restrict__ OGb)
{
    const int tid = threadIdx.x;
    const int d = tid & 63;
    const int flat = blockIdx.x * 4 + (tid >> 6);   // [0, 8*4096)
    const int h = flat >> 12;
    const int q = flat & (NN - 1);

    float l = 0.0f, o = 0.0f;
    #pragma unroll
    for (int sp = 0; sp < KSPLIT; sp++) {
        size_t idx = (size_t)(sp * 8 + h) * NN + q;
        l += Lpart[idx];
        o += bf2f(Opart[idx * 64 + d]);
    }
    float inv = 1.0f / l;
    int col = h * DD + d;
    float g = bf2f(Gb[(size_t)q * HD + col]);
    OGb[(size_t)q * HD + col] = f2bf(o * inv * g);
}

// ---------------------------------------------------------------------------
// Kernel 3: outproj split-K partials. OG[4096][512] @ wob^T, K-range per sp.
// grid (64,4,KSPLIT_O) = 1024 blocks = 4/CU. fp32 partials -> Psum[sp][m][n].
// ---------------------------------------------------------------------------
__global__ __launch_bounds__(256, 4) void outproj_kernel(
    const unsigned short* __restrict__ OGb, const unsigned short* __restrict__ wob,
    float* __restrict__ Psum)
{
    const int m0 = blockIdx.x * 64;
    const int n0 = blockIdx.y * 64;
    const int sp = blockIdx.z;
    const int tid = threadIdx.x;
    const int wid = tid >> 6;
    const int lane = tid & 63;
    const int quad = lane >> 4;
    const int ln = lane & 15;
    const int lnx = ln & 7;

    __shared__ __align__(16) unsigned short Xs[64 * 64];
    __shared__ __align__(16) unsigned short Ws[64 * 64];

    floatx4 acc[4] = {};

    const int kbeg = sp * (HD / KSPLIT_O);
    for (int k0 = kbeg; k0 < kbeg + HD / KSPLIT_O; k0 += 64) {
        #pragma unroll
        for (int t = 0; t < 2; t++) {
            int row = wid * 16 + t * 8 + (lane >> 3);
            int c = (lane & 7) ^ (lane >> 3);
            GLOAD_LDS(&OGb[(size_t)(m0 + row) * HD + k0 + c * 8],
                      &Xs[(wid * 16 + t * 8) * 64]);
            GLOAD_LDS(&wob[(size_t)(n0 + row) * HD + k0 + c * 8],
                      &Ws[(wid * 16 + t * 8) * 64]);
        }
        __syncthreads();

        #pragma unroll
        for (int ks = 0; ks < 64; ks += 32) {
            const int cb = ks >> 3;
            short8 a = *(const short8*)&Xs[(wid * 16 + ln) * 64 +
                                           (((quad ^ cb) ^ lnx) * 8)];
            #pragma unroll
            for (int n = 0; n < 4; n++) {
                short8 b = *(const short8*)&Ws[(n * 16 + ln) * 64 +
                                               (((quad ^ cb) ^ lnx) * 8)];
                acc[n] = __builtin_amdgcn_mfma_f32_16x16x32_bf16(a, b, acc[n], 0, 0, 0);
            }
        }
        __syncthreads();
    }

    float* P = Psum + (size_t)sp * NN * CC;
    #pragma unroll
    for (int n = 0; n < 4; n++) {
        int col = n0 + n * 16 + ln;
        #pragma unroll
        for (int r = 0; r < 4; r++) {
            int row = m0 + wid * 16 + quad * 4 + r;
            P[(size_t)row * CC + col] = acc[n][r];
        }
    }
}

// ---------------------------------------------------------------------------
// Kernel 3b: out = sum_sp Psum[sp] + bo -> fp32
// ---------------------------------------------------------------------------
__global__ __launch_bounds__(256) void outfinal_kernel(
    const float* __restrict__ Psum, const float* __restrict__ bo,
    float* __restrict__ out)
{
    int i = (blockIdx.x * 256 + threadIdx.x) * 4;   // flat over 4096*256
    float4 s = *(const float4*)&Psum[i];
    #pragma unroll
    for (int sp = 1; sp < KSPLIT_O; sp++) {
        float4 p = *(const float4*)&Psum[(size_t)sp * NN * CC + i];
        s.x += p.x; s.y += p.y; s.z += p.z; s.w += p.w;
    }
    int col = i & (CC - 1);
    float4 b = *(const float4*)&bo[col];
    s.x += b.x; s.y += b.y; s.z += b.z; s.w += b.w;
    *(float4*)&out[i] = s;
}

// ---------------------------------------------------------------------------
extern "C" void kernel_launch(void* const* d_in, const int* in_sizes, int n_in,
                              void* d_out, int out_size, void* d_ws, size_t ws_size,
                              hipStream_t stream) {
    const float* qx   = (const float*)d_in[0];
    const float* kx   = (const float*)d_in[1];
    const float* vx   = (const float*)d_in[2];
    const float* bias = (const float*)d_in[3];
    const float* wq   = (const float*)d_in[4];
    const float* wk   = (const float*)d_in[5];
    const float* wv   = (const float*)d_in[6];
    const float* wg   = (const float*)d_in[7];
    const float* bg   = (const float*)d_in[8];
    const float* wo   = (const float*)d_in[9];
    const float* bo   = (const float*)d_in[10];
    float* out = (float*)d_out;

    // Workspace (peak ~37.8 MB). Region at +21 MB is triple-purposed over
    // the kernel sequence: prep buffers (qxb/kxb/vxb/Wb, dead after proj)
    // -> Opart (dead after combine) -> Psum (outproj partials).
    char* ws = (char*)d_ws;
    const size_t MB = (size_t)1 << 20;
    unsigned short* wob   = (unsigned short*)(ws);                 // 0.25 MB
    float*          Lpart = (float*)(ws + MB / 4);                 // 0.4 MB
    unsigned short* Qb    = (unsigned short*)(ws + 1 * MB);        // 4 MB
    unsigned short* Kb    = (unsigned short*)(ws + 5 * MB);        // 4 MB
    unsigned short* VbT   = (unsigned short*)(ws + 9 * MB);        // 4 MB [512][4096]
    unsigned short* Gb    = (unsigned short*)(ws + 13 * MB);       // 4 MB
    unsigned short* OGb   = (unsigned short*)(ws + 17 * MB);       // 4 MB
    unsigned short* qxb   = (unsigned short*)(ws + 21 * MB);       // 2 MB (dead after proj)
    unsigned short* kxb   = (unsigned short*)(ws + 23 * MB);       // 2 MB (dead after proj)
    unsigned short* vxb   = (unsigned short*)(ws + 25 * MB);       // 2 MB (dead after proj)
    unsigned short* Wb    = (unsigned short*)(ws + 27 * MB);       // 1 MB (dead after proj)
    unsigned short* Opart = (unsigned short*)(ws + 21 * MB);       // 12.6 MB (overlay)
    float*          Psum  = (float*)(ws + 21 * MB);                // 16.8 MB (overlay)

    prep_kernel<<<dim3(NN * CC / (256 * 4), 8), 256, 0, stream>>>(
        qx, kx, vx, wq, wk, wv, wg, wo, qxb, kxb, vxb, Wb, wob);
    proj_kernel<<<dim3(64, 16), 256, 0, stream>>>(
        qxb, kxb, vxb, Wb, bg, Qb, Kb, VbT, Gb);
    attn_kernel<<<dim3(64, 8, KSPLIT), 256, 0, stream>>>(
        Qb, Kb, VbT, bias, Opart, Lpart);
    combine_kernel<<<dim3(NN * 8 / 4), 256, 0, stream>>>(
        Opart, Lpart, Gb, OGb);
    outproj_kernel<<<dim3(64, 4, KSPLIT_O), 256, 0, stream>>>(
        OGb, wob, Psum);
    outfinal_kernel<<<dim3(NN * CC / (256 * 4)), 256, 0, stream>>>(
        Psum, bo, out);
}